// Round 10
// baseline (977.164 us; speedup 1.0000x reference)
//
#include <hip/hip_runtime.h>
#include <hip/hip_bf16.h>
#include <math.h>

#define NTOK 8192     // B*T
#define DD   1024
#define HH   4096
#define NE   8
#define BM 256
#define BN 256
#define SLOT_CAP (2 * NTOK + NE * BM)   // 18432

typedef __bf16 bf16;
typedef __bf16 bf16x8 __attribute__((ext_vector_type(8)));
typedef __bf16 bf16x4 __attribute__((ext_vector_type(4)));
typedef float  f32x4  __attribute__((ext_vector_type(4)));

typedef __attribute__((address_space(3))) unsigned char lds_u8;
typedef const __attribute__((address_space(1))) unsigned char g_u8;

__device__ __forceinline__ void gload16(const bf16* g, bf16* l) {
  __builtin_amdgcn_global_load_lds((g_u8*)g, (lds_u8*)l, 16, 0, 0);
}

__device__ __forceinline__ float softplus_f(float v) {
  return fmaxf(v, 0.f) + log1pf(expf(-fabsf(v)));
}

// ---------------- K1: gating (1 wave/token), float4-vectorized, + x->bf16 ----------------
__global__ __launch_bounds__(64) void moe_gate_kernel(
    const float* __restrict__ x, const float* __restrict__ noise,
    const float* __restrict__ gate_w, const float* __restrict__ gate_b,
    const float* __restrict__ var_w,  const float* __restrict__ var_b,
    float* __restrict__ coef2, int* __restrict__ t2e, int* __restrict__ counts,
    bf16* __restrict__ xb)
{
  const int t = blockIdx.x;
  const int lane = threadIdx.x;
  const float4* x4 = (const float4*)(x + (size_t)t * DD);
  bf16x4* xb4 = (bf16x4*)(xb + (size_t)t * DD);
  const float4* gw4 = (const float4*)gate_w;
  const float4* vw4 = (const float4*)var_w;
  float pg[NE], pv[NE];
  #pragma unroll
  for (int e = 0; e < NE; ++e) { pg[e] = 0.f; pv[e] = 0.f; }
  #pragma unroll
  for (int i = 0; i < DD / 256; ++i) {
    const int d4 = i * 64 + lane;
    const float4 f = x4[d4];
    bf16x4 v;
    v[0] = (bf16)f.x; v[1] = (bf16)f.y; v[2] = (bf16)f.z; v[3] = (bf16)f.w;
    xb4[d4] = v;
    #pragma unroll
    for (int e = 0; e < NE; ++e) {
      const float4 g = gw4[e * 256 + d4];
      pg[e] = fmaf(f.x, g.x, fmaf(f.y, g.y, fmaf(f.z, g.z, fmaf(f.w, g.w, pg[e]))));
      const float4 w = vw4[e * 256 + d4];
      pv[e] = fmaf(f.x, w.x, fmaf(f.y, w.y, fmaf(f.z, w.z, fmaf(f.w, w.w, pv[e]))));
    }
  }
  #pragma unroll
  for (int e = 0; e < NE; ++e) {
    #pragma unroll
    for (int off = 32; off; off >>= 1) {
      pg[e] += __shfl_xor(pg[e], off);
      pv[e] += __shfl_xor(pv[e], off);
    }
  }
  if (lane == 0) {
    float noisy[NE];
    #pragma unroll
    for (int e = 0; e < NE; ++e) {
      const float lg = pg[e] + gate_b[e];
      const float sd = softplus_f(pv[e] + var_b[e]);
      noisy[e] = lg + noise[t * NE + e] * sd;
    }
    int i1 = 0; float n1 = noisy[0];
    #pragma unroll
    for (int e = 1; e < NE; ++e) if (noisy[e] > n1) { n1 = noisy[e]; i1 = e; }
    int i2 = -1; float n2 = -3.0e38f;
    #pragma unroll
    for (int e = 0; e < NE; ++e) if (e != i1 && noisy[e] > n2) { n2 = noisy[e]; i2 = e; }
    const float e2 = expf(n2 - n1);
    const float den = 1.f + e2;
    coef2[t * 2 + 0] = 1.f / den;
    coef2[t * 2 + 1] = e2 / den;
    t2e[t * 2 + 0] = i1;
    t2e[t * 2 + 1] = i2;
    atomicAdd(&counts[i1], 1);
    atomicAdd(&counts[i2], 1);
  }
}

// ---------------- K2: padded segment offsets (pad to BM=256) ----------------
__global__ void moe_offsets_kernel(const int* __restrict__ counts, int* __restrict__ po) {
  if (threadIdx.x == 0) {
    int acc = 0;
    po[0] = 0;
    for (int e = 0; e < NE; ++e) {
      acc += ((counts[e] + BM - 1) / BM) * BM;
      po[e + 1] = acc;
    }
  }
}

// ---------------- K3: scatter tokens into padded slots ----------------
__global__ __launch_bounds__(256) void moe_scatter_kernel(
    const int* __restrict__ t2e, const float* __restrict__ coef2,
    const int* __restrict__ po, int* __restrict__ cnt2,
    int* __restrict__ assign_tok, float* __restrict__ slot_coef)
{
  const int t = blockIdx.x * 256 + threadIdx.x;
  if (t >= NTOK) return;
  #pragma unroll
  for (int k = 0; k < 2; ++k) {
    const int e = t2e[t * 2 + k];
    const int pos = atomicAdd(&cnt2[e], 1);
    const int slot = po[e] + pos;
    assign_tok[slot] = t;
    slot_coef[slot] = coef2[t * 2 + k];
  }
}

// ---------------- K4: dual f32 -> bf16 converter ----------------
__global__ __launch_bounds__(256) void cvt2_bf16_kernel(
    const float* __restrict__ s1, bf16* __restrict__ d1, int n41,
    const float* __restrict__ s2, bf16* __restrict__ d2, int n42)
{
  for (int i = blockIdx.x * 256 + threadIdx.x; i < n41 + n42; i += gridDim.x * 256) {
    const float* s = (i < n41) ? s1 : s2;
    bf16* d = (i < n41) ? d1 : d2;
    const int j = (i < n41) ? i : i - n41;
    const float4 f = ((const float4*)s)[j];
    bf16x4 v;
    v[0] = (bf16)f.x; v[1] = (bf16)f.y; v[2] = (bf16)f.z; v[3] = (bf16)f.w;
    ((bf16x4*)d)[j] = v;
  }
}

#define VM8  asm volatile("s_waitcnt vmcnt(8)" ::: "memory")
#define VM0  asm volatile("s_waitcnt vmcnt(0)" ::: "memory")
#define BARR __builtin_amdgcn_s_barrier()

// ---------------- grouped GEMM: 256^2, 8 waves, 8-phase counted-vmcnt (m201 port) ----------------
// LDS per operand: [2 bufs][2 K-halves][256 rows][4 chunks of 16B] (64 KB); tile 2t->buf0,
// 2t+1->buf1. Swizzle: phys_chunk = logical ^ ((row>>1)&3)  (2-way bank alias only = free).
// 8 stage events/iter (1/phase, 2 gload16/thread each), FIFO ledger:
//   P1:A-Khi(2t+1) P2:B-Khi(2t+1) P3:A-Klo(2t+2) P4:B-Klo(2t+2)
//   P5:A-Khi(2t+2) P6:B-Khi(2t+2) P7:A-Klo(2t+3) P8:B-Klo(2t+3)
// Reads: P1/P2: tile 2t Klo; P3/P4: 2t Khi; P5/P6: 2t+1 Klo; P7/P8: 2t+1 Khi —
// every read's data was staged 5-6 phases earlier. Odd phases: vmcnt(8) (outstanding
// is always 12 loads; retires exactly the 2 events being read). Prologue = 6 events:
// A/B-Klo(0), A/B-Khi(0), A/B-Klo(1) -> iter 0 follows the identical pattern.
// Last iter stages wrap ((2t+2)&(NT-1)) — same free-discipline, harmless refetch.
template<int KDIM, int KSTRIDE, int NCOLS, bool FFN1>
__global__ __launch_bounds__(512, 2) void moe_gemm8_kernel(
    const bf16* __restrict__ Asrc, const bf16* __restrict__ Wsrc,
    const float* __restrict__ bias,
    const int* __restrict__ assign_tok, const float* __restrict__ slot_coef,
    const int* __restrict__ po,
    bf16* __restrict__ hout, float* __restrict__ out,
    int chunk_base, int gx)
{
  constexpr int NT = KDIM / 64;   // K-tiles (16)
  constexpr int NI = NT / 2;      // iterations (8)
  __shared__ bf16 smA[32768];     // 64 KB
  __shared__ bf16 smB[32768];     // 64 KB
  __shared__ int toks[BM];

  // bijective XCD chunk swizzle (m204)
  const int nwg = gridDim.x;
  const int lin = blockIdx.x;
  const int q = nwg >> 3, r = nwg & 7;
  const int xcd = lin & 7, idx = lin >> 3;
  const int wg = (xcd < r ? xcd * (q + 1) : r * (q + 1) + (xcd - r) * q) + idx;
  int bx, by;
  if constexpr (FFN1) { bx = wg % gx; by = wg / gx; }
  else               { by = wg % (NCOLS / BN); bx = wg / (NCOLS / BN); }

  const int po8 = po[NE];
  const int row0 = chunk_base + bx * BM;
  if (row0 >= po8) return;
  int e = 0;
  while (row0 >= po[e + 1]) ++e;
  const int bn0 = by * BN;
  const size_t kbase = (size_t)blockIdx.z * KDIM;
  const bf16* We = Wsrc + (size_t)e * ((size_t)HH * DD) + kbase;
  const bf16* As = Asrc + kbase;

  const int tid = threadIdx.x, lane = tid & 63, wid = tid >> 6;
  if (tid < BM) toks[tid] = assign_tok[row0 + tid];
  __syncthreads();   // full drain; publishes toks

  // ---- staging pointers: slot s = j*512+tid -> row r = s>>2, phys chunk s&3,
  //      logical chunk c = (s&3) ^ ((r>>1)&3)  (same c for j=0,1) ----
  const int r0 = tid >> 2, r1 = 128 + (tid >> 2);
  const int cc = (((tid & 3) ^ ((tid >> 3) & 3)) * 8);
  int ar0, ar1;
  if constexpr (FFN1) {
    const int s0 = toks[r0]; ar0 = s0 < 0 ? 0 : s0;
    const int s1 = toks[r1]; ar1 = s1 < 0 ? 0 : s1;
  } else {
    ar0 = row0 - chunk_base + r0;
    ar1 = row0 - chunk_base + r1;
  }
  const bf16* pA0 = As + (size_t)ar0 * KSTRIDE + cc;
  const bf16* pA1 = As + (size_t)ar1 * KSTRIDE + cc;
  const bf16* pB0 = We + (size_t)(bn0 + r0) * KSTRIDE + cc;
  const bf16* pB1 = We + (size_t)(bn0 + r1) * KSTRIDE + cc;

  // one stage event = one K-half of A or B = exactly 2 gload16 per thread
  auto SA = [&](int buf, int h, int kt) {
    const int ko = kt * 64 + h * 32;
    bf16* d = smA + buf * 16384 + h * 8192 + tid * 8;
    gload16(pA0 + ko, d);
    gload16(pA1 + ko, d + 4096);
  };
  auto SB = [&](int buf, int h, int kt) {
    const int ko = kt * 64 + h * 32;
    bf16* d = smB + buf * 16384 + h * 8192 + tid * 8;
    gload16(pB0 + ko, d);
    gload16(pB1 + ko, d + 4096);
  };

  // ---- fragment read bases ----
  const int wr = wid >> 2, wc = wid & 3;   // 2(M) x 4(N) wave grid
  const int la = lane & 15, hi = lane >> 4;
  const int cph = ((hi ^ ((la >> 1) & 3)) * 8);
  const int aB = (wr * 128 + la) * 32 + cph;   // + q*2048 + mm*512
  const int bB = (wc * 64 + la) * 32 + cph;    // + n*512

  bf16x8 aF[4], aG[4], bF[4];
  auto RA = [&](bf16x8* d, int buf, int ks, int qq) {
    #pragma unroll
    for (int mm = 0; mm < 4; ++mm)
      d[mm] = *(const bf16x8*)(smA + buf * 16384 + ks * 8192 + aB + qq * 2048 + mm * 512);
  };
  auto RB = [&](bf16x8* d, int buf, int ks) {
    #pragma unroll
    for (int n = 0; n < 4; ++n)
      d[n] = *(const bf16x8*)(smB + buf * 16384 + ks * 8192 + bB + n * 512);
  };

  f32x4 acc[8][4];
  #pragma unroll
  for (int m = 0; m < 8; ++m)
    #pragma unroll
    for (int n = 0; n < 4; ++n) acc[m][n] = {0.f, 0.f, 0.f, 0.f};

  auto MM = [&](bf16x8* a, bf16x8* b, int mb) {
    __builtin_amdgcn_s_setprio(1);
    #pragma unroll
    for (int mm = 0; mm < 4; ++mm)
      #pragma unroll
      for (int n = 0; n < 4; ++n)
        acc[mb + mm][n] = __builtin_amdgcn_mfma_f32_16x16x32_bf16(a[mm], b[n], acc[mb + mm][n], 0, 0, 0);
    __builtin_amdgcn_s_setprio(0);
  };

  // prologue: 6 events (12 loads outstanding at first odd-phase wait)
  SA(0, 0, 0); SB(0, 0, 0);   // tile 0 Klo
  SA(0, 1, 0); SB(0, 1, 0);   // tile 0 Khi
  SA(1, 0, 1); SB(1, 0, 1);   // tile 1 Klo

  for (int t = 0; t < NI; ++t) {
    const int t1 = 2 * t + 1;
    const int w2 = (2 * t + 2) & (NT - 1);
    const int w3 = (2 * t + 3) & (NT - 1);
    // P1: tile 2t, Klo, q0
    VM8; BARR; RA(aF, 0, 0, 0); RB(bF, 0, 0); SA(1, 1, t1); MM(aF, bF, 0);
    // P2: tile 2t, Klo, q1
    BARR; RA(aG, 0, 0, 1); SB(1, 1, t1); MM(aG, bF, 4);
    // P3: tile 2t, Khi, q0
    VM8; BARR; RA(aF, 0, 1, 0); RB(bF, 0, 1); SA(0, 0, w2); MM(aF, bF, 0);
    // P4: tile 2t, Khi, q1
    BARR; RA(aG, 0, 1, 1); SB(0, 0, w2); MM(aG, bF, 4);
    // P5: tile 2t+1, Klo, q0
    VM8; BARR; RA(aF, 1, 0, 0); RB(bF, 1, 0); SA(0, 1, w2); MM(aF, bF, 0);
    // P6: tile 2t+1, Klo, q1
    BARR; RA(aG, 1, 0, 1); SB(0, 1, w2); MM(aG, bF, 4);
    // P7: tile 2t+1, Khi, q0
    VM8; BARR; RA(aF, 1, 1, 0); RB(bF, 1, 1); SA(1, 0, w3); MM(aF, bF, 0);
    // P8: tile 2t+1, Khi, q1
    BARR; RA(aG, 1, 1, 1); SB(1, 0, w3); MM(aG, bF, 4);
  }
  VM0;   // drain wrapped tail stages

  if constexpr (FFN1) {
    const int hrow0 = row0 - chunk_base;
    #pragma unroll
    for (int n = 0; n < 4; ++n) {
      const int col = bn0 + wc * 64 + n * 16 + la;
      const float bb = bias[e * NCOLS + col];
      #pragma unroll
      for (int m = 0; m < 8; ++m) {
        const int rl = wr * 128 + m * 16 + hi * 4;
        #pragma unroll
        for (int rr = 0; rr < 4; ++rr) {
          float v = acc[m][n][rr] + bb;
          v = v > 0.f ? v : 0.f;
          hout[(size_t)(hrow0 + rl + rr) * HH + col] = (bf16)v;
        }
      }
    }
  } else {
    const bool addb = (blockIdx.z == 0);
    #pragma unroll
    for (int n = 0; n < 4; ++n) {
      const int col = bn0 + wc * 64 + n * 16 + la;
      const float bb = addb ? bias[e * NCOLS + col] : 0.f;
      #pragma unroll
      for (int m = 0; m < 8; ++m) {
        const int rl = wr * 128 + m * 16 + hi * 4;
        #pragma unroll
        for (int rr = 0; rr < 4; ++rr) {
          const int tl = rl + rr;
          const int tok = toks[tl];
          if (tok >= 0) {
            const float c = slot_coef[row0 + tl];
            atomicAdd(out + (size_t)tok * DD + col, c * (acc[m][n][rr] + bb));
          }
        }
      }
    }
  }
}

extern "C" void kernel_launch(void* const* d_in, const int* in_sizes, int n_in,
                              void* d_out, int out_size, void* d_ws, size_t ws_size,
                              hipStream_t stream) {
  const float* x      = (const float*)d_in[0];
  const float* noise  = (const float*)d_in[1];
  const float* gate_w = (const float*)d_in[2];
  const float* gate_b = (const float*)d_in[3];
  const float* var_w  = (const float*)d_in[4];
  const float* var_b  = (const float*)d_in[5];
  const float* w1     = (const float*)d_in[6];
  const float* b1     = (const float*)d_in[7];
  const float* w2     = (const float*)d_in[8];
  const float* b2     = (const float*)d_in[9];
  float* out = (float*)d_out;
  (void)in_sizes; (void)n_in; (void)out_size;

  char* ws = (char*)d_ws;
  size_t off = 0;
  auto alloc = [&](size_t bytes) {
    off = (off + 255) & ~(size_t)255;
    size_t o = off;
    off += bytes;
    return o;
  };
  bf16*  xb         = (bf16*)(ws + alloc((size_t)NTOK * DD * 2));
  float* coef2      = (float*)(ws + alloc((size_t)NTOK * 2 * 4));
  int*   t2e        = (int*)(ws + alloc((size_t)NTOK * 2 * 4));
  int*   counts     = (int*)(ws + alloc(64));   // counts[8] + cnt2[8]
  int*   cnt2       = counts + 8;
  int*   po         = (int*)(ws + alloc(64));
  int*   assign_tok = (int*)(ws + alloc((size_t)SLOT_CAP * 4));
  float* slot_coef  = (float*)(ws + alloc((size_t)SLOT_CAP * 4));
  bf16*  w1b        = (bf16*)(ws + alloc((size_t)NE * HH * DD * 2));  // 64 MB
  bf16*  w2b        = (bf16*)(ws + alloc((size_t)NE * DD * HH * 2));  // 64 MB
  off = (off + 255) & ~(size_t)255;
  const size_t h_avail = ws_size > off ? ws_size - off : 0;
  int chunk_rows = (int)(h_avail / ((size_t)HH * 2));
  chunk_rows = (chunk_rows / BM) * BM;
  if (chunk_rows < BM) chunk_rows = BM;
  if (chunk_rows > SLOT_CAP) chunk_rows = SLOT_CAP;
  bf16* hbuf = (bf16*)(ws + off);

  hipMemsetAsync(counts, 0, 64, stream);
  hipMemsetAsync(assign_tok, 0xFF, (size_t)SLOT_CAP * 4, stream);  // -1
  hipMemsetAsync(out, 0, (size_t)NTOK * DD * 4, stream);

  moe_gate_kernel<<<NTOK, 64, 0, stream>>>(x, noise, gate_w, gate_b, var_w, var_b,
                                           coef2, t2e, counts, xb);
  moe_offsets_kernel<<<1, 64, 0, stream>>>(counts, po);
  moe_scatter_kernel<<<NTOK / 256, 256, 0, stream>>>(t2e, coef2, po, cnt2,
                                                     assign_tok, slot_coef);
  cvt2_bf16_kernel<<<2048, 256, 0, stream>>>(w1, w1b, NE * HH * DD / 4,
                                             w2, w2b, NE * DD * HH / 4);

  const int rounds = (SLOT_CAP + chunk_rows - 1) / chunk_rows;
  for (int r = 0; r < rounds; ++r) {
    const int cb = r * chunk_rows;
    const int rows_here = (cb + chunk_rows <= SLOT_CAP) ? chunk_rows : (SLOT_CAP - cb);
    const int gx = rows_here / BM;
    dim3 g1(gx * (HH / BN), 1, 1);
    moe_gemm8_kernel<DD, DD, HH, true><<<g1, 512, 0, stream>>>(
        xb, w1b, b1, assign_tok, slot_coef, po, hbuf, nullptr, cb, gx);
    dim3 g2(gx * (DD / BN), 1, 4);   // K split x4 (1024 per split)
    moe_gemm8_kernel<HH / 4, HH, DD, false><<<g2, 512, 0, stream>>>(
        hbuf, w2b, b2, assign_tok, slot_coef, po, nullptr, out, cb, gx);
  }
}